// Round 6
// baseline (319.320 us; speedup 1.0000x reference)
//
#include <hip/hip_runtime.h>
#include <cstdint>
#include <cstddef>

typedef unsigned short u16;
typedef unsigned u32;
typedef unsigned long long u64;
typedef __attribute__((ext_vector_type(8))) short short8;
typedef __attribute__((ext_vector_type(4))) float f32x4;

#define T_SEQ 2048
#define DM    2048
#define NHEAD 16
#define NKV   4
#define HD    128
#define NEGBIG (-3.0e38f)
// 1/sqrt(128) * log2(e): softmax runs in exp2 domain
#define QSCALE 0.1275525165017459f
// -log2(1e6)/64 for inv_freq = 2^(d * L2IF)
#define L2IF (-0.31143258583318043f)

__device__ __forceinline__ u16 f2bf(float f) {
  union { float f; unsigned u; } c; c.f = f;
  return (u16)((c.u + 0x7fffu + ((c.u >> 16) & 1u)) >> 16);
}
__device__ __forceinline__ float bf2f(u16 b) {
  union { float f; unsigned u; } c; c.u = ((unsigned)b) << 16;
  return c.f;
}
__device__ __forceinline__ void gl_lds16(const u16* g, u16* l) {
  __builtin_amdgcn_global_load_lds(
      (const __attribute__((address_space(1))) void*)g,
      (__attribute__((address_space(3))) void*)l, 16, 0, 0);
}

// Scheduling walls WITHOUT memory clobbers: sched_barrier(0) pins compile-time
// order; bare s_barrier / s_waitcnt avoid SIInsertWaitcnts' conservative
// vmcnt(0) drain at memory-clobber asm (the round-5 stall).
#define SB0() __builtin_amdgcn_sched_barrier(0)
#define BARW() do { SB0(); __builtin_amdgcn_s_barrier(); SB0(); } while (0)
#define WAITV2() do { SB0(); asm volatile("s_waitcnt vmcnt(2)"); SB0(); } while (0)
#define WAITV0() do { SB0(); asm volatile("s_waitcnt vmcnt(0)"); SB0(); } while (0)

// ---------------- fused cast fp32 -> bf16 (all 5 tensors, dst contiguous) ---
__global__ void castk_all(const float* __restrict__ x, const float* __restrict__ wq,
                          const float* __restrict__ wk, const float* __restrict__ wv,
                          const float* __restrict__ wo, u16* __restrict__ dst) {
  long long i4 = (long long)blockIdx.x * 256 + threadIdx.x;  // unit = 4 elems
  const float* src; long long off;
  if (i4 < (2LL << 20))                    { src = x;  off = i4; }
  else if (i4 < (3LL << 20))               { src = wq; off = i4 - (2LL << 20); }
  else if (i4 < (3LL << 20) + (1 << 18))   { src = wk; off = i4 - (3LL << 20); }
  else if (i4 < (3LL << 20) + (2 << 18))   { src = wv; off = i4 - (3LL << 20) - (1 << 18); }
  else                                     { src = wo; off = i4 - (3LL << 20) - (2 << 18); }
  float4 v = *(const float4*)(src + off * 4);
  u16* d = dst + i4 * 4;
  d[0] = f2bf(v.x); d[1] = f2bf(v.y); d[2] = f2bf(v.z); d[3] = f2bf(v.w);
}

// ---------------- RoPE cos/sin table: Tab[t*64 + d] = {cos, sin}(t * invfreq(d))
__global__ void tabk(float2* __restrict__ Tab) {
  int idx = blockIdx.x * 256 + threadIdx.x;     // 2048*64 entries
  float ang = (float)(idx >> 6) * exp2f((float)(idx & 63) * L2IF);
  float sn, cs;
  sincosf(ang, &sn, &cs);
  Tab[idx] = make_float2(cs, sn);
}

// ---------------- RoPE in-place on K only ([rows, HD] bf16), table-driven ---
__global__ void ropek(u16* __restrict__ buf, const float2* __restrict__ Tab) {
  int idx = blockIdx.x * 256 + threadIdx.x;
  int r = idx >> 6, i = idx & 63;
  int t = r & (T_SEQ - 1);
  float2 cs = Tab[(t << 6) + i];
  size_t base = (size_t)r * HD + i;
  float x1 = bf2f(buf[base]), x2 = bf2f(buf[base + 64]);
  buf[base]      = f2bf(x1 * cs.x - x2 * cs.y);
  buf[base + 64] = f2bf(x2 * cs.x + x1 * cs.y);
}

// ---- GEMM LDS geometry: rows of 64 bf16 (128 B), 8 slots of 16 B.
// phys_slot = logical ^ (row&7) -> conflict-free b128 fragment reads.
// LDS dest of global_load_lds stays LINEAR; the global SOURCE column carries
// the same involution (both-sides rule). Staging unit = 64 rows.

template <int FH>
__device__ __forceinline__ void mfma_quad(f32x4 (&acc)[8][4], const short8 (&af)[4],
                                          const short8 (&bfr)[4]) {
#pragma unroll
  for (int i = 0; i < 4; ++i)
#pragma unroll
    for (int j = 0; j < 4; ++j)
      acc[FH * 4 + i][j] =
          __builtin_amdgcn_mfma_f32_16x16x32_bf16(af[i], bfr[j], acc[FH * 4 + i][j], 0, 0, 0);
}

// ---------------- 4-phase 256^2 GEMM: C[M,N] = A[M,K] @ Bm[N,K]^T ----------
// BM=BN=256, BK=64, 512 thr (8 waves, 2x4), per-wave 128x64 out.
// Per K-tile t (reads buf[t&1]), phases = (k-window W, fm-half):
//   ph1 (W0,fm0-3): ds 8 | stage (t+1).SA1,SA3
//   ph2 (W0,fm4-7): ds 4 | stage (t+1).SB0,SB1
//   ph3 (W1,fm0-3): ds 8 | stage (t+1).SB2,SB3
//   ph4 (W1,fm4-7): ds 4 | stage (t+2).SA0,SA2 -> buf[cur]; vmcnt(2) = drain
//                     t+1, keep t+2 in flight (counted, never 0 mid-loop)
__global__ __launch_bounds__(512, 2) void gemm8(
    const u16* __restrict__ A, const u16* __restrict__ Bm,
    void* __restrict__ Out0, u16* __restrict__ OutK, u16* __restrict__ OutV,
    int M, int N, int K) {
  __shared__ __align__(16) u16 AS[2][256 * 64];
  __shared__ __align__(16) u16 BS[2][256 * 64];
  const int tid = threadIdx.x;
  const int l = tid & 63, lm = l & 15, q = l >> 4;
  const int w = tid >> 6, wr = w >> 2, wc = w & 3;
  // XCD chunked swizzle (nwg=192, chunk=24), group-by-by: A-panels L2-resident
  const int nid = (blockIdx.x & 7) * 24 + (blockIdx.x >> 3);
  const int by = nid / 12, bx = nid - by * 12;
  const int m0 = by * 256, n0 = bx * 256;
  const u16* Ab = A + (size_t)m0 * K;
  const u16* Bb = Bm + (size_t)n0 * K;

  // staging: unit u = rows u*64..u*64+63; thread -> row = u*64+(tid>>3),
  // slot = tid&7; source col = (slot ^ (row&7))*8 elems; LDS dest linear.
  const int srow = tid >> 3;
  const int scol = ((tid & 7) ^ (srow & 7)) * 8;
  const int rsw = lm & 7;  // fragment-row & 7 (base rows are multiples of 8)

#define STG_A(T, U) \
  gl_lds16(Ab + (size_t)((U) * 64 + srow) * K + (T) * 64 + scol, \
           &AS[(T) & 1][((U) * 512 + tid) * 8])
#define STG_B(T, U) \
  gl_lds16(Bb + (size_t)((U) * 64 + srow) * K + (T) * 64 + scol, \
           &BS[(T) & 1][((U) * 512 + tid) * 8])

  f32x4 acc[8][4] = {};
  const int nt = K >> 6;  // 32 for K=2048

  // prologue: tile0 all 8 units, then tile1.SA0,SA2 (mimics ph4(-1))
  STG_A(0, 0); STG_A(0, 2); STG_A(0, 1); STG_A(0, 3);
  STG_B(0, 0); STG_B(0, 1); STG_B(0, 2); STG_B(0, 3);
  STG_A(1, 0); STG_A(1, 2);
  WAITV2();
  BARW();

  for (int t = 0; t < nt; ++t) {
    const int cur = t & 1;
    short8 bfr[4];

    // ---- ph1: W=0, fm0-3 ----
    {
      short8 af[4];
#pragma unroll
      for (int i = 0; i < 4; ++i)
        bfr[i] = *(const short8*)(&BS[cur][(wc * 64 + i * 16 + lm) * 64 + (q ^ rsw) * 8]);
#pragma unroll
      for (int i = 0; i < 4; ++i)
        af[i] = *(const short8*)(&AS[cur][(wr * 128 + i * 16 + lm) * 64 + (q ^ rsw) * 8]);
      if (t + 1 < nt) { STG_A(t + 1, 1); STG_A(t + 1, 3); }
      BARW();
      __builtin_amdgcn_s_setprio(1);
      mfma_quad<0>(acc, af, bfr);
      __builtin_amdgcn_s_setprio(0);
      BARW();
    }
    // ---- ph2: W=0, fm4-7 ----
    {
      short8 af[4];
#pragma unroll
      for (int i = 0; i < 4; ++i)
        af[i] = *(const short8*)(&AS[cur][(wr * 128 + (4 + i) * 16 + lm) * 64 + (q ^ rsw) * 8]);
      if (t + 1 < nt) { STG_B(t + 1, 0); STG_B(t + 1, 1); }
      BARW();
      __builtin_amdgcn_s_setprio(1);
      mfma_quad<1>(acc, af, bfr);
      __builtin_amdgcn_s_setprio(0);
      BARW();
    }
    // ---- ph3: W=1, fm0-3 ----
    {
      short8 af[4];
#pragma unroll
      for (int i = 0; i < 4; ++i)
        bfr[i] = *(const short8*)(&BS[cur][(wc * 64 + i * 16 + lm) * 64 + ((4 + q) ^ rsw) * 8]);
#pragma unroll
      for (int i = 0; i < 4; ++i)
        af[i] = *(const short8*)(&AS[cur][(wr * 128 + i * 16 + lm) * 64 + ((4 + q) ^ rsw) * 8]);
      if (t + 1 < nt) { STG_B(t + 1, 2); STG_B(t + 1, 3); }
      BARW();
      __builtin_amdgcn_s_setprio(1);
      mfma_quad<0>(acc, af, bfr);
      __builtin_amdgcn_s_setprio(0);
      BARW();
    }
    // ---- ph4: W=1, fm4-7 ----
    {
      short8 af[4];
#pragma unroll
      for (int i = 0; i < 4; ++i)
        af[i] = *(const short8*)(&AS[cur][(wr * 128 + (4 + i) * 16 + lm) * 64 + ((4 + q) ^ rsw) * 8]);
      if (t + 2 < nt) { STG_A(t + 2, 0); STG_A(t + 2, 2); }
      BARW();
      __builtin_amdgcn_s_setprio(1);
      mfma_quad<1>(acc, af, bfr);
      __builtin_amdgcn_s_setprio(0);
      if (t < nt - 2) { WAITV2(); } else { WAITV0(); }
      BARW();
    }
  }
#undef STG_A
#undef STG_B

  // epilogue: m = m0 + wr*128 + fm*16 + q*4 + r ; n = n0 + wc*64 + fn*16 + lm
  const int MODE = (N == 3072) ? 3 : 0;
#pragma unroll
  for (int fm = 0; fm < 8; ++fm)
#pragma unroll
    for (int fn = 0; fn < 4; ++fn)
#pragma unroll
      for (int r = 0; r < 4; ++r) {
        int m = m0 + wr * 128 + fm * 16 + q * 4 + r;
        int n = n0 + wc * 64 + fn * 16 + lm;
        float v = acc[fm][fn][r];
        if (MODE == 0) {
          ((float*)Out0)[(size_t)m * N + n] = v;
        } else {
          int b = m >> 11, tt = m & (T_SEQ - 1);
          if (n < 2048) {
            int h = n >> 7, d = n & (HD - 1);
            ((u16*)Out0)[(((size_t)(b * NHEAD + h)) * T_SEQ + tt) * HD + d] = f2bf(v * QSCALE);
          } else if (n < 2560) {
            int nn = n - 2048, h = nn >> 7, d = nn & (HD - 1);
            OutK[(((size_t)(b * NKV + h)) * T_SEQ + tt) * HD + d] = f2bf(v);
          } else {
            int nn = n - 2560, h = nn >> 7, d = nn & (HD - 1);
            OutV[(((size_t)(b * NKV + h)) * HD + d) * T_SEQ + tt] = f2bf(v);
          }
        }
      }
}

// ---------------- 4-phase 128x256 GEMM (fp32 out), 256 blocks = exact fill --
// BM=128, BN=256, 8 waves (2M x 4N), per-wave 64x64, acc[4][4], 8 MFMA/phase.
//   ph1 (W0,j0-1): ds 6 | stage (t+1).SB0,SB1
//   ph2 (W0,j2-3): ds 2 | stage (t+1).SB2,SB3
//   ph3 (W1,j0-1): ds 6 | -
//   ph4 (W1,j2-3): ds 2 | stage (t+2).SA0,SA1 -> buf[cur]; vmcnt(2)
__global__ __launch_bounds__(512, 2) void gemm8n(
    const u16* __restrict__ A, const u16* __restrict__ Bm,
    float* __restrict__ Out, int M, int N, int K) {
  __shared__ __align__(16) u16 AS[2][128 * 64];
  __shared__ __align__(16) u16 BS[2][256 * 64];
  const int tid = threadIdx.x;
  const int l = tid & 63, lm = l & 15, q = l >> 4;
  const int w = tid >> 6, wr = w >> 2, wc = w & 3;
  // XCD chunked swizzle (nwg=256, chunk=32), group-by-by (gx=8)
  const int nid = (blockIdx.x & 7) * 32 + (blockIdx.x >> 3);
  const int by = nid >> 3, bx = nid & 7;
  const int m0 = by * 128, n0 = bx * 256;
  const u16* Ab = A + (size_t)m0 * K;
  const u16* Bb = Bm + (size_t)n0 * K;

  const int srow = tid >> 3;
  const int scol = ((tid & 7) ^ (srow & 7)) * 8;
  const int rsw = lm & 7;

#define STG_A(T, U) \
  gl_lds16(Ab + (size_t)((U) * 64 + srow) * K + (T) * 64 + scol, \
           &AS[(T) & 1][((U) * 512 + tid) * 8])
#define STG_B(T, U) \
  gl_lds16(Bb + (size_t)((U) * 64 + srow) * K + (T) * 64 + scol, \
           &BS[(T) & 1][((U) * 512 + tid) * 8])

  f32x4 acc[4][4] = {};
  const int nt = K >> 6;

  // prologue: tile0 (6 units), tile1.SA0,SA1 (mimics ph4(-1))
  STG_A(0, 0); STG_A(0, 1);
  STG_B(0, 0); STG_B(0, 1); STG_B(0, 2); STG_B(0, 3);
  STG_A(1, 0); STG_A(1, 1);
  WAITV2();
  BARW();

  for (int t = 0; t < nt; ++t) {
    const int cur = t & 1;
    short8 af[4];

    // ---- ph1: W=0, j0-1 ----
    {
      short8 bfr[2];
#pragma unroll
      for (int j = 0; j < 2; ++j)
        bfr[j] = *(const short8*)(&BS[cur][(wc * 64 + j * 16 + lm) * 64 + (q ^ rsw) * 8]);
#pragma unroll
      for (int i = 0; i < 4; ++i)
        af[i] = *(const short8*)(&AS[cur][(wr * 64 + i * 16 + lm) * 64 + (q ^ rsw) * 8]);
      if (t + 1 < nt) { STG_B(t + 1, 0); STG_B(t + 1, 1); }
      BARW();
      __builtin_amdgcn_s_setprio(1);
#pragma unroll
      for (int i = 0; i < 4; ++i)
#pragma unroll
        for (int j = 0; j < 2; ++j)
          acc[i][j] = __builtin_amdgcn_mfma_f32_16x16x32_bf16(af[i], bfr[j], acc[i][j], 0, 0, 0);
      __builtin_amdgcn_s_setprio(0);
      BARW();
    }
    // ---- ph2: W=0, j2-3 ----
    {
      short8 bfr[2];
#pragma unroll
      for (int j = 0; j < 2; ++j)
        bfr[j] = *(const short8*)(&BS[cur][(wc * 64 + (2 + j) * 16 + lm) * 64 + (q ^ rsw) * 8]);
      if (t + 1 < nt) { STG_B(t + 1, 2); STG_B(t + 1, 3); }
      BARW();
      __builtin_amdgcn_s_setprio(1);
#pragma unroll
      for (int i = 0; i < 4; ++i)
#pragma unroll
        for (int j = 0; j < 2; ++j)
          acc[i][2 + j] = __builtin_amdgcn_mfma_f32_16x16x32_bf16(af[i], bfr[j], acc[i][2 + j], 0, 0, 0);
      __builtin_amdgcn_s_setprio(0);
      BARW();
    }
    // ---- ph3: W=1, j0-1 ----
    {
      short8 bfr[2];
#pragma unroll
      for (int j = 0; j < 2; ++j)
        bfr[j] = *(const short8*)(&BS[cur][(wc * 64 + j * 16 + lm) * 64 + ((4 + q) ^ rsw) * 8]);
#pragma unroll
      for (int i = 0; i < 4; ++i)
        af[i] = *(const short8*)(&AS[cur][(wr * 64 + i * 16 + lm) * 64 + ((4 + q) ^ rsw) * 8]);
      BARW();
      __builtin_amdgcn_s_setprio(1);
#pragma unroll
      for (int i = 0; i < 4; ++i)
#pragma unroll
        for (int j = 0; j < 2; ++j)
          acc[i][j] = __builtin_amdgcn_mfma_f32_16x16x32_bf16(af[i], bfr[j], acc[i][j], 0, 0, 0);
      __builtin_amdgcn_s_setprio(0);
      BARW();
    }
    // ---- ph4: W=1, j2-3 ----
    {
      short8 bfr[2];
#pragma unroll
      for (int j = 0; j < 2; ++j)
        bfr[j] = *(const short8*)(&BS[cur][(wc * 64 + (2 + j) * 16 + lm) * 64 + ((4 + q) ^ rsw) * 8]);
      if (t + 2 < nt) { STG_A(t + 2, 0); STG_A(t + 2, 1); }
      BARW();
      __builtin_amdgcn_s_setprio(1);
#pragma unroll
      for (int i = 0; i < 4; ++i)
#pragma unroll
        for (int j = 0; j < 2; ++j)
          acc[i][2 + j] = __builtin_amdgcn_mfma_f32_16x16x32_bf16(af[i], bfr[j], acc[i][2 + j], 0, 0, 0);
      __builtin_amdgcn_s_setprio(0);
      if (t < nt - 2) { WAITV2(); } else { WAITV0(); }
      BARW();
    }
  }
#undef STG_A
#undef STG_B

#pragma unroll
  for (int fm = 0; fm < 4; ++fm)
#pragma unroll
    for (int fn = 0; fn < 4; ++fn)
#pragma unroll
      for (int r = 0; r < 4; ++r) {
        int m = m0 + wr * 64 + fm * 16 + q * 4 + r;
        int n = n0 + wc * 64 + fn * 16 + lm;
        Out[(size_t)m * N + n] = acc[fm][fn][r];
      }
}

// ---------------- flash attention v6 (unchanged) ---------------------------
#define PSTRIDE 72
__global__ __launch_bounds__(256, 2) void attnk(
    const u16* __restrict__ Q, const u16* __restrict__ Kh,
    const u16* __restrict__ Vt, const float2* __restrict__ Tab,
    u16* __restrict__ Oa) {
  __shared__ __align__(16) u16 Ks[2][64 * 128];   // [s][d], slot^ (s&15)
  __shared__ __align__(16) u16 Vs[2][128 * 64];   // [d][s], slot^ (d&7)
  __shared__ __align__(16) u16 Pl[4][16 * PSTRIDE];
  const int tid = threadIdx.x;
  const int w = tid >> 6, l = tid & 63, lm = l & 15, q = l >> 4;

  const int wg = blockIdx.x;             // 0..511
  const int g = wg & 7, slot = wg >> 3;  // group -> XCD, 0..63 within group
  const int b = g >> 2, kvh = g & 3;
  const int h = kvh * 4 + (slot & 3);
  const int p = slot >> 2;               // 0..15 tile-pair index

  const u16* Kb = Kh + ((size_t)(b * NKV + kvh)) * T_SEQ * HD;
  const u16* Vb = Vt + ((size_t)(b * NKV + kvh)) * HD * T_SEQ;
  u16* Pw = Pl[w];

  const int r16 = tid >> 4, c16 = tid & 15;  // K: row group, phys slot
  const int r8  = tid >> 3, c8  = tid & 7;   // V: row group, phys slot

#pragma unroll 1
  for (int half = 0; half < 2; ++half) {
    const int tile = half ? p : (31 - p);  // heavy tile first
    const int tbase = tile * 64 + w * 16;
    const u16* Qb = Q + (((size_t)(b * NHEAD + h)) * T_SEQ + tbase) * HD;

    short8 qa[4];
#pragma unroll
    for (int ks = 0; ks < 4; ++ks)
      qa[ks] = *(const short8*)(Qb + (size_t)lm * HD + ks * 32 + q * 8);

    // fused Q-RoPE from table: pair (d, d+64) is lane-local (qa[ks], qa[ks+2])
    {
      const float2* tb = Tab + (((size_t)(tbase + lm)) << 6) + q * 8;
#pragma unroll
      for (int ks = 0; ks < 2; ++ks) {
        short8 lo = qa[ks], hi = qa[ks + 2];
#pragma unroll
        for (int e = 0; e < 8; ++e) {
          float2 cs = tb[ks * 32 + e];
          float x1 = bf2f((u16)lo[e]), x2 = bf2f((u16)hi[e]);
          lo[e] = (short)f2bf(x1 * cs.x - x2 * cs.y);
          hi[e] = (short)f2bf(x2 * cs.x + x1 * cs.y);
        }
        qa[ks] = lo; qa[ks + 2] = hi;
      }
    }

    float m_i = NEGBIG, l_i = 0.f;
    f32x4 oacc[8] = {};
    const int nst = tile + 1;

    // prologue: stage step 0 into buffer 0
    {
#pragma unroll
      for (int j = 0; j < 4; ++j) {
        int s = j * 16 + r16, gs = c16 ^ (s & 15);
        gl_lds16(Kb + (size_t)s * HD + gs * 8, &Ks[0][s * 128 + c16 * 8]);
      }
#pragma unroll
      for (int j = 0; j < 4; ++j) {
        int d = j * 32 + r8, gs = c8 ^ (d & 7);
        gl_lds16(Vb + (size_t)d * T_SEQ + gs * 8, &Vs[0][d * 64 + c8 * 8]);
      }
    }
    __syncthreads();

    for (int st = 0; st < nst; ++st) {
      const int bb = st & 1;
      if (st + 1 < nst) {
        const int s0n = (st + 1) * 64;
#pragma unroll
        for (int j = 0; j < 4; ++j) {
          int s = j * 16 + r16, gs = c16 ^ (s & 15);
          gl_lds16(Kb + (size_t)(s0n + s) * HD + gs * 8, &Ks[bb ^ 1][s * 128 + c16 * 8]);
        }
#pragma unroll
        for (int j = 0; j < 4; ++j) {
          int d = j * 32 + r8, gs = c8 ^ (d & 7);
          gl_lds16(Vb + (size_t)d * T_SEQ + s0n + gs * 8, &Vs[bb ^ 1][d * 64 + c8 * 8]);
        }
      }

      // QK^T from LDS K-tile
      f32x4 sacc[4] = {};
#pragma unroll
      for (int ks = 0; ks < 4; ++ks)
#pragma unroll
        for (int nt = 0; nt < 4; ++nt) {
          short8 kb = *(const short8*)(&Ks[bb][(nt * 16 + lm) * 128 + ((ks * 4 + q) ^ lm) * 8]);
          sacc[nt] = __builtin_amdgcn_mfma_f32_16x16x32_bf16(kb, qa[ks], sacc[nt], 0, 0, 0);
        }

      const bool diag = (st == nst - 1);
      const int s0 = st * 64;
      float mx = NEGBIG;
#pragma unroll
      for (int nt = 0; nt < 4; ++nt)
#pragma unroll
        for (int j = 0; j < 4; ++j) {
          float v = sacc[nt][j];
          if (diag) {
            int s_abs = s0 + nt * 16 + q * 4 + j;
            if (s_abs > tbase + lm) v = NEGBIG;
            sacc[nt][j] = v;
          }
          mx = fmaxf(mx, v);
        }
      mx = fmaxf(mx, __shfl_xor(mx, 16, 64));
      mx = fmaxf(mx, __shfl_xor(mx, 32, 64));
      if (__any(mx > m_i + 8.0f)) {
        float mnew = fmaxf(m_i, mx);
        float alpha = exp2f(m_i - mnew);
        m_i = mnew;
        l_i *= alpha;
#pragma unroll
        for (int dt = 0; dt < 8; ++dt)
#pragma unroll
          for (int j = 0; j < 4; ++j) oacc[dt][j] *= alpha;
      }
      float sum = 0.f;
#pragma unroll
      for (int nt = 0; nt < 4; ++nt) {
        float e0 = exp2f(sacc[nt][0] - m_i), e1 = exp2f(sacc[nt][1] - m_i);
        float e2 = exp2f(sacc[nt][2] - m_i), e3 = exp2f(sacc[nt][3] - m_i);
        sum += (e0 + e1) + (e2 + e3);
        u32 lo32 = __builtin_amdgcn_perm(__float_as_uint(e1), __float_as_uint(e0), 0x07060302u);
        u32 hi32 = __builtin_amdgcn_perm(__float_as_uint(e3), __float_as_uint(e2), 0x07060302u);
        *(u64*)(Pw + lm * PSTRIDE + nt * 16 + q * 4) = ((u64)hi32 << 32) | lo32;
      }
      sum += __shfl_xor(sum, 16, 64);
      sum += __shfl_xor(sum, 32, 64);
      l_i += sum;

      asm volatile("" ::: "memory");

      // PV from LDS V-tile: O^T += V^T · P~
#pragma unroll
      for (int ks = 0; ks < 2; ++ks) {
        short8 pa = *(const short8*)(Pw + lm * PSTRIDE + ks * 32 + q * 8);
#pragma unroll
        for (int dt = 0; dt < 8; ++dt) {
          short8 vb = *(const short8*)(
              &Vs[bb][(dt * 16 + lm) * 64 + ((ks * 4 + q) ^ (lm & 7)) * 8]);
          oacc[dt] = __builtin_amdgcn_mfma_f32_16x16x32_bf16(vb, pa, oacc[dt], 0, 0, 0);
        }
      }
      __syncthreads();
    }

    float inv = 1.0f / l_i;
    int t = tbase + lm;
#pragma unroll
    for (int dt = 0; dt < 8; ++dt) {
      u16 ok[4];
#pragma unroll
      for (int j = 0; j < 4; ++j) ok[j] = f2bf(oacc[dt][j] * inv);
      *(u64*)(Oa + ((size_t)(b * T_SEQ + t)) * (NHEAD * HD) + h * HD + dt * 16 + q * 4) =
          (u64)ok[0] | ((u64)ok[1] << 16) | ((u64)ok[2] << 32) | ((u64)ok[3] << 48);
    }
  }
}

extern "C" void kernel_launch(void* const* d_in, const int* in_sizes, int n_in,
                              void* d_out, int out_size, void* d_ws, size_t ws_size,
                              hipStream_t stream) {
  const float* x  = (const float*)d_in[0];
  const float* wq = (const float*)d_in[1];
  const float* wk = (const float*)d_in[2];
  const float* wv = (const float*)d_in[3];
  const float* wo = (const float*)d_in[4];
  float* out = (float*)d_out;

  u16* ws  = (u16*)d_ws;
  u16* xb  = ws;                      // 8M elems  (x bf16)  [later: attn out]
  u16* wqb = xb  + (8u << 20);        // 4M   } contiguous
  u16* wkb = wqb + (4u << 20);        // 1M   }  -> fused QKV weight [3072,2048]
  u16* wvb = wkb + (1u << 20);        // 1M   }
  u16* wob = wvb + (1u << 20);        // 4M
  u16* Qb  = wob + (4u << 20);        // 8M
  u16* Kb  = Qb  + (8u << 20);        // 2M
  u16* Vtb = Kb  + (2u << 20);        // 2M
  u16* Ab  = xb;                      // alias: 8M  (total 30M elems = 60 MB)
  float2* tab = (float2*)wkb;         // 1 MB table overlays dead wkb

  // 1. fused cast
  castk_all<<<18432, 256, 0, stream>>>(x, wq, wk, wv, wo, ws);

  // 2. fused QKV projection: [4096,2048] @ [3072,2048]^T, 192 blocks 1-D
  gemm8<<<192, 512, 0, stream>>>(xb, wqb, Qb, Kb, Vtb, 4096, 3072, 2048);

  // 3. RoPE cos/sin table, then RoPE on K
  tabk<<<512, 256, 0, stream>>>(tab);
  ropek<<<4096, 256, 0, stream>>>(Kb, tab);

  // 4. attention: 512 blocks, XCD-pinned KV groups (wgid&7)
  attnk<<<512, 256, 0, stream>>>(Qb, Kb, Vtb, tab, Ab);

  // 5. output projection -> fp32 d_out, 256 blocks 1-D = exact fill
  gemm8n<<<256, 512, 0, stream>>>(Ab, wob, out, 4096, 2048, 2048);
}

// Round 7
// 291.335 us; speedup vs baseline: 1.0961x; 1.0961x over previous
//
#include <hip/hip_runtime.h>
#include <cstdint>
#include <cstddef>

typedef unsigned short u16;
typedef unsigned u32;
typedef unsigned long long u64;
typedef __attribute__((ext_vector_type(8))) short short8;
typedef __attribute__((ext_vector_type(4))) float f32x4;

#define T_SEQ 2048
#define DM    2048
#define NHEAD 16
#define NKV   4
#define HD    128
#define NEGBIG (-3.0e38f)
// 1/sqrt(128) * log2(e): softmax runs in exp2 domain
#define QSCALE 0.1275525165017459f
// -log2(1e6)/64 for inv_freq = 2^(d * L2IF)
#define L2IF (-0.31143258583318043f)

__device__ __forceinline__ u16 f2bf(float f) {
  union { float f; unsigned u; } c; c.f = f;
  return (u16)((c.u + 0x7fffu + ((c.u >> 16) & 1u)) >> 16);
}
__device__ __forceinline__ float bf2f(u16 b) {
  union { float f; unsigned u; } c; c.u = ((unsigned)b) << 16;
  return c.f;
}
__device__ __forceinline__ void gl_lds16(const u16* g, u16* l) {
  __builtin_amdgcn_global_load_lds(
      (const __attribute__((address_space(1))) void*)g,
      (__attribute__((address_space(3))) void*)l, 16, 0, 0);
}

// ---------------- fused cast fp32 -> bf16 (all 5 tensors, dst contiguous) ---
__global__ void castk_all(const float* __restrict__ x, const float* __restrict__ wq,
                          const float* __restrict__ wk, const float* __restrict__ wv,
                          const float* __restrict__ wo, u16* __restrict__ dst) {
  long long i4 = (long long)blockIdx.x * 256 + threadIdx.x;  // unit = 4 elems
  const float* src; long long off;
  if (i4 < (2LL << 20))                    { src = x;  off = i4; }
  else if (i4 < (3LL << 20))               { src = wq; off = i4 - (2LL << 20); }
  else if (i4 < (3LL << 20) + (1 << 18))   { src = wk; off = i4 - (3LL << 20); }
  else if (i4 < (3LL << 20) + (2 << 18))   { src = wv; off = i4 - (3LL << 20) - (1 << 18); }
  else                                     { src = wo; off = i4 - (3LL << 20) - (2 << 18); }
  float4 v = *(const float4*)(src + off * 4);
  u16* d = dst + i4 * 4;
  d[0] = f2bf(v.x); d[1] = f2bf(v.y); d[2] = f2bf(v.z); d[3] = f2bf(v.w);
}

// ---------------- RoPE cos/sin table: Tab[t*64 + d] = {cos, sin}(t * invfreq(d))
__global__ void tabk(float2* __restrict__ Tab) {
  int idx = blockIdx.x * 256 + threadIdx.x;     // 2048*64 entries
  float ang = (float)(idx >> 6) * exp2f((float)(idx & 63) * L2IF);
  float sn, cs;
  sincosf(ang, &sn, &cs);
  Tab[idx] = make_float2(cs, sn);
}

// ---------------- RoPE in-place on K only ([rows, HD] bf16), table-driven ---
__global__ void ropek(u16* __restrict__ buf, const float2* __restrict__ Tab) {
  int idx = blockIdx.x * 256 + threadIdx.x;
  int r = idx >> 6, i = idx & 63;
  int t = r & (T_SEQ - 1);
  float2 cs = Tab[(t << 6) + i];
  size_t base = (size_t)r * HD + i;
  float x1 = bf2f(buf[base]), x2 = bf2f(buf[base + 64]);
  buf[base]      = f2bf(x1 * cs.x - x2 * cs.y);
  buf[base + 64] = f2bf(x2 * cs.x + x1 * cs.y);
}

// ---------------- GEMM: C[M,N] = A[M,K] @ Bm[N,K]^T  (bf16 in, MFMA) -------
// ROUND-1 STRUCTURE (measured 77 us): 128^2 tile, BK=32, 256 thr (4 waves 2x2,
// per-wave 64x64), LDS 32 KB -> 3+ blocks/CU so cross-block wave overlap hides
// the per-iter barrier drain (m114). Two pure-addressing edits on top:
//  1. LDS swizzle: row-major [128][32] bf16 (64B rows, 4 slots of 16B);
//     phys slot holds logical quarter (slot ^ ((row>>1)&3)). LDS dest of
//     global_load_lds stays LINEAR; the SOURCE column is pre-swizzled with
//     the same involution; fragment reads apply it on the read side.
//     Quarter-wave lanes then cover all 8 (row-parity, slot) bank windows,
//     2 lanes each = conflict-free ds_read_b128 (round-3-verified: 0 conflicts).
//  2. XCD-chunked block swizzle (bijective: nwg % 8 == 0): consecutive wgids
//     round-robin XCDs, so chunk = nwg/8 gives each XCD a contiguous nid
//     range grouped by M-panel -> A panels L2-resident, B via L3.
// MODE 0: fp32 plain row-major out (Out0)
// MODE 3: fused QKV epilogue: n<2048 -> Q [B,NH,T,HD] *QSCALE;
//         n<2560 -> K [B,NKV,T,HD]; else V^T [B,NKV,HD,T]
template <int MODE>
__global__ __launch_bounds__(256) void gemm_bt(
    const u16* __restrict__ A, const u16* __restrict__ Bm,
    void* __restrict__ Out0, u16* __restrict__ OutK, u16* __restrict__ OutV,
    int M, int N, int K) {
  __shared__ __align__(16) u16 As[2][128 * 32];
  __shared__ __align__(16) u16 Bs[2][128 * 32];
  const int tid = threadIdx.x;
  const int w = tid >> 6, l = tid & 63;
  const int lm = l & 15, q = l >> 4;
  // XCD-chunked bijective swizzle: nwg = gridDim.x (multiple of 8)
  const int chunk = gridDim.x >> 3;
  const int nid = (blockIdx.x & 7) * chunk + (blockIdx.x >> 3);
  const int nbx = N >> 7;
  const int by = nid / nbx, bx = nid - by * nbx;
  const int m0 = by * 128, n0 = bx * 128;
  const int mq = w & 1, nq = w >> 1;
  const u16* Ab = A + (size_t)m0 * K;
  const u16* Bb = Bm + (size_t)n0 * K;

  // staging decomposition: slot s -> row = s>>2, phys 16B-slot = s&3.
  // swizzled SOURCE col = ((s&3) ^ ((s>>3)&3)) * 8 elems (16B units)
  const int s0_ = w * 64 + l, s1_ = 256 + s0_;
  const int row0 = s0_ >> 2, sc0 = (((s0_ & 3) ^ ((s0_ >> 3) & 3))) * 8;
  const int row1 = s1_ >> 2, sc1 = (((s1_ & 3) ^ ((s1_ >> 3) & 3))) * 8;
  const int rs = (lm >> 1) & 3;  // read-side swizzle term

  f32x4 acc[4][4] = {};
  const int nk = K >> 5;

  // prologue: stage k-tile 0 into buffer 0
  gl_lds16(Ab + (size_t)row0 * K + sc0, &As[0][s0_ * 8]);
  gl_lds16(Bb + (size_t)row0 * K + sc0, &Bs[0][s0_ * 8]);
  gl_lds16(Ab + (size_t)row1 * K + sc1, &As[0][s1_ * 8]);
  gl_lds16(Bb + (size_t)row1 * K + sc1, &Bs[0][s1_ * 8]);
  __syncthreads();

  for (int ki = 0; ki < nk; ++ki) {
    const int bb = ki & 1;
    if (ki + 1 < nk) {  // prefetch next k-tile into other buffer
      const int k0 = (ki + 1) << 5;
      gl_lds16(Ab + (size_t)row0 * K + k0 + sc0, &As[bb ^ 1][s0_ * 8]);
      gl_lds16(Bb + (size_t)row0 * K + k0 + sc0, &Bs[bb ^ 1][s0_ * 8]);
      gl_lds16(Ab + (size_t)row1 * K + k0 + sc1, &As[bb ^ 1][s1_ * 8]);
      gl_lds16(Bb + (size_t)row1 * K + k0 + sc1, &Bs[bb ^ 1][s1_ * 8]);
    }
    short8 af[4], bf[4];
#pragma unroll
    for (int i = 0; i < 4; ++i) {
      af[i] = *(const short8*)(&As[bb][(mq * 64 + i * 16 + lm) * 32 + (q ^ rs) * 8]);
      bf[i] = *(const short8*)(&Bs[bb][(nq * 64 + i * 16 + lm) * 32 + (q ^ rs) * 8]);
    }
#pragma unroll
    for (int i = 0; i < 4; ++i)
#pragma unroll
      for (int j = 0; j < 4; ++j)
        acc[i][j] = __builtin_amdgcn_mfma_f32_16x16x32_bf16(af[i], bf[j], acc[i][j], 0, 0, 0);
    __syncthreads();  // next iter's buffer writes are fenced by this barrier
  }

#pragma unroll
  for (int i = 0; i < 4; ++i)
#pragma unroll
    for (int j = 0; j < 4; ++j)
#pragma unroll
      for (int r = 0; r < 4; ++r) {
        int m = m0 + mq * 64 + i * 16 + q * 4 + r;
        int n = n0 + nq * 64 + j * 16 + lm;
        float v = acc[i][j][r];
        if constexpr (MODE == 0) {
          ((float*)Out0)[(size_t)m * N + n] = v;
        } else {
          int b = m >> 11, t = m & (T_SEQ - 1);
          if (n < 2048) {
            int h = n >> 7, d = n & (HD - 1);
            ((u16*)Out0)[(((size_t)(b * NHEAD + h)) * T_SEQ + t) * HD + d] = f2bf(v * QSCALE);
          } else if (n < 2560) {
            int nn = n - 2048, h = nn >> 7, d = nn & (HD - 1);
            OutK[(((size_t)(b * NKV + h)) * T_SEQ + t) * HD + d] = f2bf(v);
          } else {
            int nn = n - 2560, h = nn >> 7, d = nn & (HD - 1);
            OutV[(((size_t)(b * NKV + h)) * HD + d) * T_SEQ + t] = f2bf(v);
          }
        }
      }
}

// ---------------- flash attention v6 (unchanged) ---------------------------
#define PSTRIDE 72
__global__ __launch_bounds__(256, 2) void attnk(
    const u16* __restrict__ Q, const u16* __restrict__ Kh,
    const u16* __restrict__ Vt, const float2* __restrict__ Tab,
    u16* __restrict__ Oa) {
  __shared__ __align__(16) u16 Ks[2][64 * 128];   // [s][d], slot^ (s&15)
  __shared__ __align__(16) u16 Vs[2][128 * 64];   // [d][s], slot^ (d&7)
  __shared__ __align__(16) u16 Pl[4][16 * PSTRIDE];
  const int tid = threadIdx.x;
  const int w = tid >> 6, l = tid & 63, lm = l & 15, q = l >> 4;

  const int wg = blockIdx.x;             // 0..511
  const int g = wg & 7, slot = wg >> 3;  // group -> XCD, 0..63 within group
  const int b = g >> 2, kvh = g & 3;
  const int h = kvh * 4 + (slot & 3);
  const int p = slot >> 2;               // 0..15 tile-pair index

  const u16* Kb = Kh + ((size_t)(b * NKV + kvh)) * T_SEQ * HD;
  const u16* Vb = Vt + ((size_t)(b * NKV + kvh)) * HD * T_SEQ;
  u16* Pw = Pl[w];

  const int r16 = tid >> 4, c16 = tid & 15;  // K: row group, phys slot
  const int r8  = tid >> 3, c8  = tid & 7;   // V: row group, phys slot

#pragma unroll 1
  for (int half = 0; half < 2; ++half) {
    const int tile = half ? p : (31 - p);  // heavy tile first
    const int tbase = tile * 64 + w * 16;
    const u16* Qb = Q + (((size_t)(b * NHEAD + h)) * T_SEQ + tbase) * HD;

    short8 qa[4];
#pragma unroll
    for (int ks = 0; ks < 4; ++ks)
      qa[ks] = *(const short8*)(Qb + (size_t)lm * HD + ks * 32 + q * 8);

    // fused Q-RoPE from table: pair (d, d+64) is lane-local (qa[ks], qa[ks+2])
    {
      const float2* tb = Tab + (((size_t)(tbase + lm)) << 6) + q * 8;
#pragma unroll
      for (int ks = 0; ks < 2; ++ks) {
        short8 lo = qa[ks], hi = qa[ks + 2];
#pragma unroll
        for (int e = 0; e < 8; ++e) {
          float2 cs = tb[ks * 32 + e];
          float x1 = bf2f((u16)lo[e]), x2 = bf2f((u16)hi[e]);
          lo[e] = (short)f2bf(x1 * cs.x - x2 * cs.y);
          hi[e] = (short)f2bf(x2 * cs.x + x1 * cs.y);
        }
        qa[ks] = lo; qa[ks + 2] = hi;
      }
    }

    float m_i = NEGBIG, l_i = 0.f;
    f32x4 oacc[8] = {};
    const int nst = tile + 1;

    // prologue: stage step 0 into buffer 0
    {
#pragma unroll
      for (int j = 0; j < 4; ++j) {
        int s = j * 16 + r16, gs = c16 ^ (s & 15);
        gl_lds16(Kb + (size_t)s * HD + gs * 8, &Ks[0][s * 128 + c16 * 8]);
      }
#pragma unroll
      for (int j = 0; j < 4; ++j) {
        int d = j * 32 + r8, gs = c8 ^ (d & 7);
        gl_lds16(Vb + (size_t)d * T_SEQ + gs * 8, &Vs[0][d * 64 + c8 * 8]);
      }
    }
    __syncthreads();

    for (int st = 0; st < nst; ++st) {
      const int bb = st & 1;
      if (st + 1 < nst) {
        const int s0n = (st + 1) * 64;
#pragma unroll
        for (int j = 0; j < 4; ++j) {
          int s = j * 16 + r16, gs = c16 ^ (s & 15);
          gl_lds16(Kb + (size_t)(s0n + s) * HD + gs * 8, &Ks[bb ^ 1][s * 128 + c16 * 8]);
        }
#pragma unroll
        for (int j = 0; j < 4; ++j) {
          int d = j * 32 + r8, gs = c8 ^ (d & 7);
          gl_lds16(Vb + (size_t)d * T_SEQ + s0n + gs * 8, &Vs[bb ^ 1][d * 64 + c8 * 8]);
        }
      }

      // QK^T from LDS K-tile
      f32x4 sacc[4] = {};
#pragma unroll
      for (int ks = 0; ks < 4; ++ks)
#pragma unroll
        for (int nt = 0; nt < 4; ++nt) {
          short8 kb = *(const short8*)(&Ks[bb][(nt * 16 + lm) * 128 + ((ks * 4 + q) ^ lm) * 8]);
          sacc[nt] = __builtin_amdgcn_mfma_f32_16x16x32_bf16(kb, qa[ks], sacc[nt], 0, 0, 0);
        }

      const bool diag = (st == nst - 1);
      const int s0 = st * 64;
      float mx = NEGBIG;
#pragma unroll
      for (int nt = 0; nt < 4; ++nt)
#pragma unroll
        for (int j = 0; j < 4; ++j) {
          float v = sacc[nt][j];
          if (diag) {
            int s_abs = s0 + nt * 16 + q * 4 + j;
            if (s_abs > tbase + lm) v = NEGBIG;
            sacc[nt][j] = v;
          }
          mx = fmaxf(mx, v);
        }
      mx = fmaxf(mx, __shfl_xor(mx, 16, 64));
      mx = fmaxf(mx, __shfl_xor(mx, 32, 64));
      if (__any(mx > m_i + 8.0f)) {
        float mnew = fmaxf(m_i, mx);
        float alpha = exp2f(m_i - mnew);
        m_i = mnew;
        l_i *= alpha;
#pragma unroll
        for (int dt = 0; dt < 8; ++dt)
#pragma unroll
          for (int j = 0; j < 4; ++j) oacc[dt][j] *= alpha;
      }
      float sum = 0.f;
#pragma unroll
      for (int nt = 0; nt < 4; ++nt) {
        float e0 = exp2f(sacc[nt][0] - m_i), e1 = exp2f(sacc[nt][1] - m_i);
        float e2 = exp2f(sacc[nt][2] - m_i), e3 = exp2f(sacc[nt][3] - m_i);
        sum += (e0 + e1) + (e2 + e3);
        u32 lo32 = __builtin_amdgcn_perm(__float_as_uint(e1), __float_as_uint(e0), 0x07060302u);
        u32 hi32 = __builtin_amdgcn_perm(__float_as_uint(e3), __float_as_uint(e2), 0x07060302u);
        *(u64*)(Pw + lm * PSTRIDE + nt * 16 + q * 4) = ((u64)hi32 << 32) | lo32;
      }
      sum += __shfl_xor(sum, 16, 64);
      sum += __shfl_xor(sum, 32, 64);
      l_i += sum;

      asm volatile("" ::: "memory");

      // PV from LDS V-tile: O^T += V^T · P~
#pragma unroll
      for (int ks = 0; ks < 2; ++ks) {
        short8 pa = *(const short8*)(Pw + lm * PSTRIDE + ks * 32 + q * 8);
#pragma unroll
        for (int dt = 0; dt < 8; ++dt) {
          short8 vb = *(const short8*)(
              &Vs[bb][(dt * 16 + lm) * 64 + ((ks * 4 + q) ^ (lm & 7)) * 8]);
          oacc[dt] = __builtin_amdgcn_mfma_f32_16x16x32_bf16(vb, pa, oacc[dt], 0, 0, 0);
        }
      }
      __syncthreads();
    }

    float inv = 1.0f / l_i;
    int t = tbase + lm;
#pragma unroll
    for (int dt = 0; dt < 8; ++dt) {
      u16 ok[4];
#pragma unroll
      for (int j = 0; j < 4; ++j) ok[j] = f2bf(oacc[dt][j] * inv);
      *(u64*)(Oa + ((size_t)(b * T_SEQ + t)) * (NHEAD * HD) + h * HD + dt * 16 + q * 4) =
          (u64)ok[0] | ((u64)ok[1] << 16) | ((u64)ok[2] << 32) | ((u64)ok[3] << 48);
    }
  }
}

extern "C" void kernel_launch(void* const* d_in, const int* in_sizes, int n_in,
                              void* d_out, int out_size, void* d_ws, size_t ws_size,
                              hipStream_t stream) {
  const float* x  = (const float*)d_in[0];
  const float* wq = (const float*)d_in[1];
  const float* wk = (const float*)d_in[2];
  const float* wv = (const float*)d_in[3];
  const float* wo = (const float*)d_in[4];
  float* out = (float*)d_out;

  u16* ws  = (u16*)d_ws;
  u16* xb  = ws;                      // 8M elems  (x bf16)  [later: attn out]
  u16* wqb = xb  + (8u << 20);        // 4M   } contiguous
  u16* wkb = wqb + (4u << 20);        // 1M   }  -> fused QKV weight [3072,2048]
  u16* wvb = wkb + (1u << 20);        // 1M   }
  u16* wob = wvb + (1u << 20);        // 4M
  u16* Qb  = wob + (4u << 20);        // 8M
  u16* Kb  = Qb  + (8u << 20);        // 2M
  u16* Vtb = Kb  + (2u << 20);        // 2M
  u16* Ab  = xb;                      // alias: 8M  (total 30M elems = 60 MB)
  float2* tab = (float2*)wkb;         // 1 MB table overlays dead wkb

  // 1. fused cast
  castk_all<<<18432, 256, 0, stream>>>(x, wq, wk, wv, wo, ws);

  // 2. fused QKV projection: [4096,2048] @ [3072,2048]^T, 768 blocks = 3/CU
  gemm_bt<3><<<768, 256, 0, stream>>>(xb, wqb, Qb, Kb, Vtb, 4096, 3072, 2048);

  // 3. RoPE cos/sin table, then RoPE on K
  tabk<<<512, 256, 0, stream>>>(tab);
  ropek<<<4096, 256, 0, stream>>>(Kb, tab);

  // 4. attention: 512 blocks, XCD-pinned KV groups (wgid&7)
  attnk<<<512, 256, 0, stream>>>(Qb, Kb, Vtb, tab, Ab);

  // 5. output projection -> fp32 d_out, 512 blocks
  gemm_bt<0><<<512, 256, 0, stream>>>(Ab, wob, out, nullptr, nullptr, 4096, 2048, 2048);
}